// Round 2
// baseline (959.329 us; speedup 1.0000x reference)
//
#include <hip/hip_runtime.h>

typedef __attribute__((ext_vector_type(4))) float f4;

#define NN 50000
#define NE 600000
#define HEADS 4
#define DH 32
#define HIDU 128
#define NC 10

// ---------------- CSR build ----------------
__global__ void k_zero(int* p, int n) {
    int i = blockIdx.x * blockDim.x + threadIdx.x;
    if (i < n) p[i] = 0;
}

__global__ void k_hist(const int* __restrict__ dst, int* __restrict__ deg) {
    int i = blockIdx.x * blockDim.x + threadIdx.x;
    if (i < NE) atomicAdd(&deg[dst[i]], 1);
}

__global__ __launch_bounds__(1024) void k_scan(const int* __restrict__ deg,
                                               int* __restrict__ row_ptr,
                                               int* __restrict__ cursor) {
    __shared__ int sums[1024];
    int t = threadIdx.x;
    const int CH = (NN + 1023) / 1024;  // 49
    int base = t * CH;
    int s = 0;
    for (int i = 0; i < CH; i++) { int idx = base + i; if (idx < NN) s += deg[idx]; }
    sums[t] = s;
    __syncthreads();
    for (int off = 1; off < 1024; off <<= 1) {
        int v = 0;
        if (t >= off) v = sums[t - off];
        __syncthreads();
        sums[t] += v;
        __syncthreads();
    }
    int run = sums[t] - s;  // exclusive prefix of this chunk
    for (int i = 0; i < CH; i++) {
        int idx = base + i;
        if (idx < NN) { row_ptr[idx] = run; cursor[idx] = run; run += deg[idx]; }
    }
    if (t == 1023) row_ptr[NN] = run;   // == NE
}

__global__ void k_scatter(const int* __restrict__ ei, int* __restrict__ cursor,
                          int* __restrict__ csr_src, int* __restrict__ csr_eid) {
    int i = blockIdx.x * blockDim.x + threadIdx.x;
    if (i < NE) {
        int s = ei[i];
        int d = ei[NE + i];
        int pos = atomicAdd(&cursor[d], 1);
        csr_src[pos] = s;
        csr_eid[pos] = i;
    }
}

// ---------------- fused q/k/v/s GEMM (fp32 VALU) ----------------
// out[r][c] = sum_k X[r][k] * W[k][c] + b[c];  W row-major [k][c] as given.
// grid (ceil(N/64), 4 mats); block 256 = 8 rowgroups x 32 lanes (4 cols each).
__global__ __launch_bounds__(256) void gemm_qkvs(
    const float* __restrict__ X,
    const float* __restrict__ W0, const float* __restrict__ W1,
    const float* __restrict__ W2, const float* __restrict__ W3,
    const float* __restrict__ b0, const float* __restrict__ b1,
    const float* __restrict__ b2, const float* __restrict__ b3,
    float* __restrict__ outq, float* __restrict__ outk, float* __restrict__ outv,
    float* __restrict__ outs, int nrows)
{
    const int mat = blockIdx.y;
    const float* W   = (mat == 0) ? W0 : (mat == 1) ? W1 : (mat == 2) ? W2 : W3;
    const float* bia = (mat == 0) ? b0 : (mat == 1) ? b1 : (mat == 2) ? b2 : b3;
    const int t = threadIdx.x;
    const int rg = t >> 5;          // 0..7
    const int c0 = (t & 31) * 4;    // col group
    const int row0 = blockIdx.x * 64 + rg * 8;

    const float* xp[8];
    #pragma unroll
    for (int i = 0; i < 8; i++) {
        int rr = row0 + i;
        if (rr > nrows - 1) rr = nrows - 1;   // clamp: loads stay in-bounds
        xp[i] = X + (size_t)rr * HIDU;
    }
    const float* wp = W + c0;

    float acc[8][4];
    #pragma unroll
    for (int i = 0; i < 8; i++)
        #pragma unroll
        for (int c = 0; c < 4; c++) acc[i][c] = 0.f;

    for (int k4 = 0; k4 < 32; k4++) {
        f4 w[4];
        #pragma unroll
        for (int j = 0; j < 4; j++) w[j] = *(const f4*)(wp + (size_t)(4 * k4 + j) * HIDU);
        #pragma unroll
        for (int i = 0; i < 8; i++) {
            f4 a = *(const f4*)(xp[i] + 4 * k4);
            #pragma unroll
            for (int j = 0; j < 4; j++) {
                #pragma unroll
                for (int c = 0; c < 4; c++) acc[i][c] += a[j] * w[j][c];
            }
        }
    }

    f4 bv = *(const f4*)(bia + c0);
    float* o = (mat == 0) ? outq : (mat == 1) ? outk : (mat == 2) ? outv : outs;
    #pragma unroll
    for (int i = 0; i < 8; i++) {
        int rr = row0 + i;
        if (rr < nrows) {
            f4 v;
            #pragma unroll
            for (int c = 0; c < 4; c++) v[c] = acc[i][c] + bv[c];
            *(f4*)(o + (size_t)rr * HIDU + c0) = v;
        }
    }
}

// ---------------- fused attention: one thread per (node, head) ----------------
// online softmax over incoming edges; e-embedding folded algebraically:
//   q.e = edge_attr . g   where g[t] = sum_j We[t][h*32+j]*q[j]   (per-thread precompute)
//   sum_e w*e = (sum_e w*edge_attr) @ We_h                        (epilogue transform)
__global__ __launch_bounds__(256) void attn(
    const float* __restrict__ qb, const float* __restrict__ kb, const float* __restrict__ vb,
    const float* __restrict__ sb, const float* __restrict__ eattr, const float* __restrict__ We,
    const int* __restrict__ row_ptr, const int* __restrict__ csr_src,
    const int* __restrict__ csr_eid, float* __restrict__ hout, int nnodes)
{
    __shared__ float WeS[4 * 513];   // [h][t*32+j]
    #pragma unroll
    for (int i = 0; i < 8; i++) {
        int idx = threadIdx.x + i * 256;   // t*128 + c over 16x128
        int tt = idx >> 7, c = idx & 127;
        int h = c >> 5, j = c & 31;
        WeS[h * 513 + tt * 32 + j] = We[idx];
    }
    __syncthreads();

    int tid = blockIdx.x * 256 + threadIdx.x;
    int n = tid >> 2, h = tid & 3;
    if (n >= nnodes) return;
    const float* WeH = &WeS[h * 513];

    float qreg[32];
    {
        const f4* qp = (const f4*)(qb + (size_t)n * HIDU + h * DH);
        #pragma unroll
        for (int c = 0; c < 8; c++) {
            f4 x = qp[c];
            #pragma unroll
            for (int j = 0; j < 4; j++) qreg[c * 4 + j] = x[j];
        }
    }
    float g[16];
    #pragma unroll
    for (int t16 = 0; t16 < 16; t16++) {
        float a = 0.f;
        #pragma unroll
        for (int j = 0; j < 32; j++) a += qreg[j] * WeH[t16 * 32 + j];
        g[t16] = a;
    }

    float m = -INFINITY, l = 0.f;
    float O[32];
    float a16[16];
    #pragma unroll
    for (int j = 0; j < 32; j++) O[j] = 0.f;
    #pragma unroll
    for (int t16 = 0; t16 < 16; t16++) a16[t16] = 0.f;

    const int r0 = row_ptr[n], r1 = row_ptr[n + 1];
    const float inv = 0.17677669529663687f;   // 1/sqrt(32)

    for (int e = r0; e < r1; e++) {
        int src = csr_src[e];
        int eid = csr_eid[e];
        const f4* kp = (const f4*)(kb + (size_t)src * HIDU + h * DH);
        const f4* ep = (const f4*)(eattr + (size_t)eid * 16);
        const f4* vp = (const f4*)(vb + (size_t)src * HIDU + h * DH);

        float ea[16];
        #pragma unroll
        for (int c = 0; c < 4; c++) {
            f4 x = ep[c];
            #pragma unroll
            for (int j = 0; j < 4; j++) ea[c * 4 + j] = x[j];
        }
        float dot = 0.f;
        #pragma unroll
        for (int c = 0; c < 8; c++) {
            f4 x = kp[c];
            #pragma unroll
            for (int j = 0; j < 4; j++) dot += qreg[c * 4 + j] * x[j];
        }
        #pragma unroll
        for (int t16 = 0; t16 < 16; t16++) dot += g[t16] * ea[t16];

        float logit = dot * inv;
        float mn = fmaxf(m, logit);
        float corr = __expf(m - mn);      // first edge: exp(-inf)=0
        float w = __expf(logit - mn);
        l = l * corr + w;
        #pragma unroll
        for (int c = 0; c < 8; c++) {
            f4 x = vp[c];
            #pragma unroll
            for (int j = 0; j < 4; j++) O[c * 4 + j] = O[c * 4 + j] * corr + w * x[j];
        }
        #pragma unroll
        for (int t16 = 0; t16 < 16; t16++) a16[t16] = a16[t16] * corr + w * ea[t16];
        m = mn;
    }

    float invl = 1.0f / (l + 1e-16f);     // PyG softmax eps; zero-degree -> O=0
    const float* sp = sb + (size_t)n * HIDU + h * DH;
    float* op = hout + (size_t)n * HIDU + h * DH;
    #pragma unroll
    for (int j = 0; j < 32; j++) {
        float ev = 0.f;
        #pragma unroll
        for (int t16 = 0; t16 < 16; t16++) ev += a16[t16] * WeH[t16 * 32 + j];
        float val = (O[j] + ev) * invl + sp[j];
        op[j] = fmaxf(val, 0.f);          // relu(conv_out)
    }
}

// ---------------- head: logits + log_softmax ----------------
__global__ __launch_bounds__(256) void head_out(
    const float* __restrict__ hb, const float* __restrict__ Wout, const float* __restrict__ bout,
    float* __restrict__ out, int nnodes)
{
    __shared__ float Ws[HIDU * NC];
    __shared__ float bs[NC];
    for (int i = 0; i < 5; i++) {
        int idx = threadIdx.x + i * 256;
        if (idx < HIDU * NC) Ws[idx] = Wout[idx];
    }
    if (threadIdx.x < NC) bs[threadIdx.x] = bout[threadIdx.x];
    __syncthreads();

    int n = blockIdx.x * 256 + threadIdx.x;
    if (n >= nnodes) return;

    float lg[NC];
    #pragma unroll
    for (int c = 0; c < NC; c++) lg[c] = bs[c];
    const f4* hp = (const f4*)(hb + (size_t)n * HIDU);
    #pragma unroll
    for (int kc = 0; kc < 32; kc++) {
        f4 hv = hp[kc];
        #pragma unroll
        for (int j = 0; j < 4; j++) {
            float h = hv[j];
            int kk = kc * 4 + j;
            #pragma unroll
            for (int c = 0; c < NC; c++) lg[c] += h * Ws[kk * NC + c];
        }
    }
    float mx = lg[0];
    #pragma unroll
    for (int c = 1; c < NC; c++) mx = fmaxf(mx, lg[c]);
    float sum = 0.f;
    #pragma unroll
    for (int c = 0; c < NC; c++) sum += __expf(lg[c] - mx);
    float lse = mx + __logf(sum);
    #pragma unroll
    for (int c = 0; c < NC; c++) out[(size_t)n * NC + c] = lg[c] - lse;
}

// ---------------- launch ----------------
extern "C" void kernel_launch(void* const* d_in, const int* in_sizes, int n_in,
                              void* d_out, int out_size, void* d_ws, size_t ws_size,
                              hipStream_t stream) {
    const float* x     = (const float*)d_in[0];
    const int*   ei    = (const int*)d_in[1];
    const float* eattr = (const float*)d_in[2];
    const float *Wq0 = (const float*)d_in[3],  *bq0 = (const float*)d_in[4];
    const float *Wk0 = (const float*)d_in[5],  *bk0 = (const float*)d_in[6];
    const float *Wv0 = (const float*)d_in[7],  *bv0 = (const float*)d_in[8];
    const float *We0 = (const float*)d_in[9];
    const float *Ws0 = (const float*)d_in[10], *bs0 = (const float*)d_in[11];
    const float *Wq1 = (const float*)d_in[12], *bq1 = (const float*)d_in[13];
    const float *Wk1 = (const float*)d_in[14], *bk1 = (const float*)d_in[15];
    const float *Wv1 = (const float*)d_in[16], *bv1 = (const float*)d_in[17];
    const float *We1 = (const float*)d_in[18];
    const float *Ws1 = (const float*)d_in[19], *bs1 = (const float*)d_in[20];
    const float *Wout = (const float*)d_in[21], *bout = (const float*)d_in[22];

    char* p = (char*)d_ws;
    auto alloc = [&](size_t bytes) -> void* {
        void* r = (void*)p;
        p += (bytes + 255) & ~(size_t)255;
        return r;
    };
    int* deg      = (int*)alloc(NN * 4);
    int* row_ptr  = (int*)alloc((NN + 1) * 4);
    int* cursor   = (int*)alloc(NN * 4);
    int* csr_src  = (int*)alloc(NE * 4);
    int* csr_eid  = (int*)alloc(NE * 4);
    float* qb     = (float*)alloc((size_t)NN * HIDU * 4);
    float* kb     = (float*)alloc((size_t)NN * HIDU * 4);
    float* vb     = (float*)alloc((size_t)NN * HIDU * 4);
    float* sbuf   = (float*)alloc((size_t)NN * HIDU * 4);
    float* hbuf   = (float*)alloc((size_t)NN * HIDU * 4);

    // CSR build (every call: inputs/ws are re-poisoned)
    k_zero<<<(NN + 255) / 256, 256, 0, stream>>>(deg, NN);
    k_hist<<<(NE + 255) / 256, 256, 0, stream>>>(ei + NE, deg);
    k_scan<<<1, 1024, 0, stream>>>(deg, row_ptr, cursor);
    k_scatter<<<(NE + 255) / 256, 256, 0, stream>>>(ei, cursor, csr_src, csr_eid);

    const int gm = (NN + 63) / 64;                 // 782
    const int ga = (NN * HEADS + 255) / 256;       // 782
    // layer 1
    gemm_qkvs<<<dim3(gm, 4), 256, 0, stream>>>(x, Wq0, Wk0, Wv0, Ws0,
                                               bq0, bk0, bv0, bs0, qb, kb, vb, sbuf, NN);
    attn<<<ga, 256, 0, stream>>>(qb, kb, vb, sbuf, eattr, We0,
                                 row_ptr, csr_src, csr_eid, hbuf, NN);
    // layer 2 (attn output overwrites hbuf: attn never reads it)
    gemm_qkvs<<<dim3(gm, 4), 256, 0, stream>>>(hbuf, Wq1, Wk1, Wv1, Ws1,
                                               bq1, bk1, bv1, bs1, qb, kb, vb, sbuf, NN);
    attn<<<ga, 256, 0, stream>>>(qb, kb, vb, sbuf, eattr, We1,
                                 row_ptr, csr_src, csr_eid, hbuf, NN);
    // head
    head_out<<<(NN + 255) / 256, 256, 0, stream>>>(hbuf, Wout, bout, (float*)d_out, NN);
}